// Round 7
// baseline (562.636 us; speedup 1.0000x reference)
//
#include <hip/hip_runtime.h>
#include <math.h>

typedef unsigned short ushort_t;
typedef __attribute__((ext_vector_type(8))) short bf16x8;
typedef __attribute__((ext_vector_type(4))) float f32x4;

#define Dt 768
#define Mrows 8192

__device__ __forceinline__ ushort_t f2b(float f) {
    union { float f; unsigned int u; } v; v.f = f;
    unsigned int u = v.u;
    unsigned int r = (u + 0x7fffu + ((u >> 16) & 1u)) >> 16;
    return (ushort_t)r;
}
__device__ __forceinline__ float b2f(ushort_t u) {
    union { unsigned int u; float f; } v; v.u = ((unsigned int)u) << 16;
    return v.f;
}
__device__ __forceinline__ f32x4 mfma16(bf16x8 a, bf16x8 b, f32x4 c) {
    return __builtin_amdgcn_mfma_f32_16x16x32_bf16(a, b, c, 0, 0, 0);
}
__device__ __forceinline__ float gelu_exact(float v) {
    return 0.5f * v * (1.0f + erff(v * 0.70710678118654752f));
}
__device__ __forceinline__ void gl2lds16(const ushort_t* g, ushort_t* l) {
    __builtin_amdgcn_global_load_lds((const __attribute__((address_space(1))) void*)g,
                                     (__attribute__((address_space(3))) void*)l,
                                     16, 0, 0);
}

// ---------------- batched weight transpose (6x 768x768): f32 [K][N] -> bf16 [N][K] ----
__global__ __launch_bounds__(256)
void tconv6_kernel(const float* i0, const float* i1, const float* i2,
                   const float* i3, const float* i4, const float* i5,
                   ushort_t* o0, ushort_t* o1, ushort_t* o2,
                   ushort_t* o3, ushort_t* o4, ushort_t* o5)
{
    const float* in; ushort_t* out;
    switch (blockIdx.z) {
        case 0: in = i0; out = o0; break;
        case 1: in = i1; out = o1; break;
        case 2: in = i2; out = o2; break;
        case 3: in = i3; out = o3; break;
        case 4: in = i4; out = o4; break;
        default: in = i5; out = o5; break;
    }
    __shared__ float T[32][33];
    int t = threadIdx.x;
    int n0 = blockIdx.x * 32, k0 = blockIdx.y * 32;
    int r = t >> 3, c4 = (t & 7) * 4;
    float4 v = *(const float4*)(in + (size_t)(k0 + r) * 768 + n0 + c4);
    T[r][c4] = v.x; T[r][c4 + 1] = v.y; T[r][c4 + 2] = v.z; T[r][c4 + 3] = v.w;
    __syncthreads();
    int nl = t >> 3, k4 = (t & 7) * 4;
    unsigned int lo = (unsigned int)f2b(T[k4][nl]) | ((unsigned int)f2b(T[k4 + 1][nl]) << 16);
    unsigned int hi = (unsigned int)f2b(T[k4 + 2][nl]) | ((unsigned int)f2b(T[k4 + 3][nl]) << 16);
    uint2 o; o.x = lo; o.y = hi;
    *(uint2*)(out + (size_t)(n0 + nl) * 768 + k0 + k4) = o;
}

// ---------------- generic weight transpose (Wi / Wout) ----------------
__global__ __launch_bounds__(256)
void tconv_kernel(const float* __restrict__ in, ushort_t* __restrict__ out,
                  int K, int N)
{
    __shared__ float T[32][33];
    int t = threadIdx.x;
    int n0 = blockIdx.x * 32, k0 = blockIdx.y * 32;
    int r = t >> 3, c4 = (t & 7) * 4;
    float4 v = *(const float4*)(in + (size_t)(k0 + r) * N + n0 + c4);
    T[r][c4] = v.x; T[r][c4 + 1] = v.y; T[r][c4 + 2] = v.z; T[r][c4 + 3] = v.w;
    __syncthreads();
    int nl = t >> 3, k4 = (t & 7) * 4;
    unsigned int lo = (unsigned int)f2b(T[k4][nl]) | ((unsigned int)f2b(T[k4 + 1][nl]) << 16);
    unsigned int hi = (unsigned int)f2b(T[k4 + 2][nl]) | ((unsigned int)f2b(T[k4 + 3][nl]) << 16);
    uint2 o; o.x = lo; o.y = hi;
    *(uint2*)(out + (size_t)(n0 + nl) * K + k0 + k4) = o;
}

// ---------------- bias concatenation ----------------
__global__ __launch_bounds__(256)
void bconcat_kernel(const float* bq, const float* bk, const float* bv,
                    const float* gbq, const float* gbk,
                    float* bqkv, float* gbqk)
{
    int g = blockIdx.x * 256 + threadIdx.x;
    if (g < 768)       bqkv[g] = bq[g];
    else if (g < 1536) bqkv[g] = bk[g - 768];
    else if (g < 2304) bqkv[g] = bv[g - 1536];
    else if (g < 3072) gbqk[g - 2304] = gbq[g - 2304];
    else if (g < 3840) gbqk[g - 2304] = gbk[g - 3072];
}

// ---------------- fused: xb = bf16(x), hb = bf16(LN(x)) ----------------
__global__ __launch_bounds__(256)
void lnx_kernel(const float* __restrict__ x, const float* __restrict__ g,
                const float* __restrict__ be, ushort_t* __restrict__ xb,
                ushort_t* __restrict__ hb)
{
    int row = blockIdx.x;
    const float* xr = x + (size_t)row * Dt;
    int t = threadIdx.x;
    float v0 = xr[t], v1 = xr[t + 256], v2 = xr[t + 512];
    ushort_t* xrow = xb + (size_t)row * Dt;
    xrow[t] = f2b(v0); xrow[t + 256] = f2b(v1); xrow[t + 512] = f2b(v2);
    float s = v0 + v1 + v2;
    #pragma unroll
    for (int off = 32; off; off >>= 1) s += __shfl_xor(s, off, 64);
    __shared__ float r1[4], r2[4];
    if ((t & 63) == 0) r1[t >> 6] = s;
    __syncthreads();
    float mu = (r1[0] + r1[1] + r1[2] + r1[3]) * (1.0f / Dt);
    float d0 = v0 - mu, d1 = v1 - mu, d2 = v2 - mu;
    float sq = d0 * d0 + d1 * d1 + d2 * d2;
    #pragma unroll
    for (int off = 32; off; off >>= 1) sq += __shfl_xor(sq, off, 64);
    if ((t & 63) == 0) r2[t >> 6] = sq;
    __syncthreads();
    float var = (r2[0] + r2[1] + r2[2] + r2[3]) * (1.0f / Dt);
    float rs = 1.0f / sqrtf(var + 1e-12f);
    ushort_t* hrow = hb + (size_t)row * Dt;
    hrow[t]       = f2b(d0 * rs * g[t]       + be[t]);
    hrow[t + 256] = f2b(d1 * rs * g[t + 256] + be[t + 256]);
    hrow[t + 512] = f2b(d2 * rs * g[t + 512] + be[t + 512]);
}

// ---------------- final LayerNorm (f32 in/out) ----------------
__global__ __launch_bounds__(256)
void ln_kernel(const float* __restrict__ x, const float* __restrict__ g,
               const float* __restrict__ be, float* __restrict__ out)
{
    int row = blockIdx.x;
    const float* xr = x + (size_t)row * Dt;
    int t = threadIdx.x;
    float v0 = xr[t], v1 = xr[t + 256], v2 = xr[t + 512];
    float s = v0 + v1 + v2;
    #pragma unroll
    for (int off = 32; off; off >>= 1) s += __shfl_xor(s, off, 64);
    __shared__ float r1[4], r2[4];
    if ((t & 63) == 0) r1[t >> 6] = s;
    __syncthreads();
    float mu = (r1[0] + r1[1] + r1[2] + r1[3]) * (1.0f / Dt);
    float d0 = v0 - mu, d1 = v1 - mu, d2 = v2 - mu;
    float sq = d0 * d0 + d1 * d1 + d2 * d2;
    #pragma unroll
    for (int off = 32; off; off >>= 1) sq += __shfl_xor(sq, off, 64);
    if ((t & 63) == 0) r2[t >> 6] = sq;
    __syncthreads();
    float var = (r2[0] + r2[1] + r2[2] + r2[3]) * (1.0f / Dt);
    float rs = 1.0f / sqrtf(var + 1e-12f);
    float* orow = out + (size_t)row * Dt;
    orow[t]       = d0 * rs * g[t]       + be[t];
    orow[t + 256] = d1 * rs * g[t + 256] + be[t + 256];
    orow[t + 512] = d2 * rs * g[t + 512] + be[t + 512];
}

// ---------------- bf16 MFMA GEMM: 3-deep ring + counted vmcnt + T2 swizzle ----------
// C[M,N] = A[M,K] @ Bt[N,K]^T. BM=128, BN=128, BK=32, 256 thr (2x2 waves).
// LDS linear (global_load_lds rule); bank spread via pre-swizzled GLOBAL source
// octet p^=((row>>1)&3) and matching XOR on the ds_read side (involution).
enum { EPI_BF16 = 1, EPI_QKV = 2, EPI_DUAL = 3, EPI_GELU = 4, EPI_RES = 5, EPI_ACC = 6 };

template<int EPI>
__global__ __launch_bounds__(256)
void gemm128(const ushort_t* __restrict__ A, const ushort_t* __restrict__ Bt,
             const float* __restrict__ bias, const float* __restrict__ res,
             float* __restrict__ Cf, ushort_t* __restrict__ O0,
             ushort_t* __restrict__ O1, ushort_t* __restrict__ O2,
             int K, int ldb, int ldc)
{
    constexpr int TSZ = 128 * 32;            // ushorts per tile buffer
    __shared__ ushort_t As[3 * TSZ];
    __shared__ ushort_t Bs[3 * TSZ];
    int t = threadIdx.x;
    int w = t >> 6, l = t & 63;
    int wr = w >> 1, wc = w & 1;
    int lr = l & 15, lg = l >> 4;

    // XCD-aware chunked swizzle (grids are multiples of 8)
    int nwg = gridDim.x * gridDim.y;
    int bid = blockIdx.y * gridDim.x + blockIdx.x;
    int per = nwg >> 3;
    int sw  = (bid & 7) * per + (bid >> 3);
    int bn = (sw % gridDim.x) * 128;
    int bm = (sw / gridDim.x) * 128;

    // staging addresses: thread t covers row t>>2, LDS slot t&3; global octet
    // is pre-swizzled so linear LDS ends up bank-spread on the read side.
    int srow = t >> 2;
    int soct = (t & 3) ^ ((srow >> 1) & 3);
    const ushort_t* gA0 = A + (size_t)(bm + srow) * K + (soct << 3);
    const ushort_t* gA1 = A + (size_t)(bm + 64 + srow) * K + (soct << 3);
    const ushort_t* gB0 = Bt + (size_t)(bn + srow) * ldb + (soct << 3);
    const ushort_t* gB1 = Bt + (size_t)(bn + 64 + srow) * ldb + (soct << 3);
    int woff = (w << 9);

    f32x4 acc[4][4];
    #pragma unroll
    for (int m = 0; m < 4; ++m)
        #pragma unroll
        for (int n = 0; n < 4; ++n) acc[m][n] = (f32x4)0.0f;

    int nT = K >> 5;
    // prologue: stage tiles 0,1 into buffers 0,1 (8 outstanding loads/wave)
    gl2lds16(gA0, As + woff);
    gl2lds16(gA1, As + 2048 + woff);
    gl2lds16(gB0, Bs + woff);
    gl2lds16(gB1, Bs + 2048 + woff);
    gl2lds16(gA0 + 32, As + TSZ + woff);
    gl2lds16(gA1 + 32, As + TSZ + 2048 + woff);
    gl2lds16(gB0 + 32, Bs + TSZ + woff);
    gl2lds16(gB1 + 32, Bs + TSZ + 2048 + woff);

    int cb = 0, sb = 2;
    for (int tt = 0; tt < nT; ++tt) {
        if (tt + 2 < nT) {                    // stage tile tt+2
            int k0 = (tt + 2) << 5;
            gl2lds16(gA0 + k0, As + sb * TSZ + woff);
            gl2lds16(gA1 + k0, As + sb * TSZ + 2048 + woff);
            gl2lds16(gB0 + k0, Bs + sb * TSZ + woff);
            gl2lds16(gB1 + k0, Bs + sb * TSZ + 2048 + woff);
        }
        // wait ONLY tile tt's 4 loads (issued 2 iterations ago) -- never 0
        if (tt < nT - 2)       asm volatile("s_waitcnt vmcnt(8)" ::: "memory");
        else if (tt == nT - 2) asm volatile("s_waitcnt vmcnt(4)" ::: "memory");
        else                   asm volatile("s_waitcnt vmcnt(0)" ::: "memory");
        __builtin_amdgcn_s_barrier();

        const ushort_t* Ab = As + cb * TSZ;
        const ushort_t* Bb = Bs + cb * TSZ;
        bf16x8 af[4], bfv[4];
        #pragma unroll
        for (int m = 0; m < 4; ++m) {
            int R = wr * 64 + m * 16 + lr;
            af[m] = *(const bf16x8*)&Ab[R * 32 + ((lg ^ ((R >> 1) & 3)) << 3)];
        }
        #pragma unroll
        for (int n = 0; n < 4; ++n) {
            int R = wc * 64 + n * 16 + lr;
            bfv[n] = *(const bf16x8*)&Bb[R * 32 + ((lg ^ ((R >> 1) & 3)) << 3)];
        }
        __builtin_amdgcn_s_setprio(1);
        #pragma unroll
        for (int m = 0; m < 4; ++m)
            #pragma unroll
            for (int n = 0; n < 4; ++n)
                acc[m][n] = mfma16(af[m], bfv[n], acc[m][n]);
        __builtin_amdgcn_s_setprio(0);
        __builtin_amdgcn_s_barrier();         // reads done before ring overwrite
        cb = (cb == 2) ? 0 : cb + 1;
        sb = (sb == 2) ? 0 : sb + 1;
    }

    #pragma unroll
    for (int m = 0; m < 4; ++m) {
        int row0 = bm + wr * 64 + m * 16 + lg * 4;
        #pragma unroll
        for (int n = 0; n < 4; ++n) {
            int ng = bn + wc * 64 + n * 16 + lr;
            float v0 = acc[m][n][0], v1 = acc[m][n][1];
            float v2 = acc[m][n][2], v3 = acc[m][n][3];
            if (EPI != EPI_ACC) {
                float bv = bias[ng];
                v0 += bv; v1 += bv; v2 += bv; v3 += bv;
            }
            if (EPI == EPI_BF16) {
                O0[(size_t)(row0 + 0) * ldc + ng] = f2b(v0);
                O0[(size_t)(row0 + 1) * ldc + ng] = f2b(v1);
                O0[(size_t)(row0 + 2) * ldc + ng] = f2b(v2);
                O0[(size_t)(row0 + 3) * ldc + ng] = f2b(v3);
            } else if (EPI == EPI_QKV) {
                if (bn < 768) {
                    O0[(size_t)(row0 + 0) * 768 + ng] = f2b(v0 * 0.125f);
                    O0[(size_t)(row0 + 1) * 768 + ng] = f2b(v1 * 0.125f);
                    O0[(size_t)(row0 + 2) * 768 + ng] = f2b(v2 * 0.125f);
                    O0[(size_t)(row0 + 3) * 768 + ng] = f2b(v3 * 0.125f);
                } else if (bn < 1536) {
                    int c = ng - 768;
                    O1[(size_t)(row0 + 0) * 768 + c] = f2b(v0);
                    O1[(size_t)(row0 + 1) * 768 + c] = f2b(v1);
                    O1[(size_t)(row0 + 2) * 768 + c] = f2b(v2);
                    O1[(size_t)(row0 + 3) * 768 + c] = f2b(v3);
                } else {
                    int dk = ng - 1536;
                    unsigned int lo = (unsigned int)f2b(v0) | ((unsigned int)f2b(v1) << 16);
                    unsigned int hi = (unsigned int)f2b(v2) | ((unsigned int)f2b(v3) << 16);
                    uint2 o; o.x = lo; o.y = hi;
                    *(uint2*)(O2 + (size_t)dk * Mrows + row0) = o;
                }
            } else if (EPI == EPI_DUAL) {
                Cf[(size_t)(row0 + 0) * ldc + ng] = v0;
                Cf[(size_t)(row0 + 1) * ldc + ng] = v1;
                Cf[(size_t)(row0 + 2) * ldc + ng] = v2;
                Cf[(size_t)(row0 + 3) * ldc + ng] = v3;
                O0[(size_t)(row0 + 0) * ldc + ng] = f2b(v0);
                O0[(size_t)(row0 + 1) * ldc + ng] = f2b(v1);
                O0[(size_t)(row0 + 2) * ldc + ng] = f2b(v2);
                O0[(size_t)(row0 + 3) * ldc + ng] = f2b(v3);
            } else if (EPI == EPI_GELU) {
                O0[(size_t)(row0 + 0) * ldc + ng] = f2b(gelu_exact(v0));
                O0[(size_t)(row0 + 1) * ldc + ng] = f2b(gelu_exact(v1));
                O0[(size_t)(row0 + 2) * ldc + ng] = f2b(gelu_exact(v2));
                O0[(size_t)(row0 + 3) * ldc + ng] = f2b(gelu_exact(v3));
            } else if (EPI == EPI_RES) {
                Cf[(size_t)(row0 + 0) * ldc + ng] = v0 + res[(size_t)(row0 + 0) * Dt + ng];
                Cf[(size_t)(row0 + 1) * ldc + ng] = v1 + res[(size_t)(row0 + 1) * Dt + ng];
                Cf[(size_t)(row0 + 2) * ldc + ng] = v2 + res[(size_t)(row0 + 2) * Dt + ng];
                Cf[(size_t)(row0 + 3) * ldc + ng] = v3 + res[(size_t)(row0 + 3) * Dt + ng];
            } else if (EPI == EPI_ACC) {
                Cf[(size_t)(row0 + 0) * ldc + ng] += v0;
                Cf[(size_t)(row0 + 1) * ldc + ng] += v1;
                Cf[(size_t)(row0 + 2) * ldc + ng] += v2;
                Cf[(size_t)(row0 + 3) * ldc + ng] += v3;
            }
        }
    }
}

// ---------------- group attention ----------------
__global__ __launch_bounds__(256)
void group_scores_kernel(const ushort_t* __restrict__ GQK, const int* __restrict__ am,
                         float* __restrict__ smU, float* __restrict__ smD,
                         int* __restrict__ emptyF)
{
    int gi = blockIdx.x;
    int b = gi >> 9, s = gi & 511;
    int t = threadIdx.x;
    const ushort_t* qr = GQK + (size_t)gi * 1536;
    bool hasU = (s < 511) && (am[(b << 9) + s + 1] != 0);
    bool hasD = (s > 0)   && (am[(b << 9) + s - 1] != 0);
    float su = 0.0f, sd = 0.0f;
    if (hasU) {
        const ushort_t* kr = GQK + (size_t)(gi + 1) * 1536 + 768;
        for (int c = t; c < Dt; c += 256) su += b2f(qr[c]) * b2f(kr[c]);
    }
    if (hasD) {
        const ushort_t* kr = GQK + (size_t)(gi - 1) * 1536 + 768;
        for (int c = t; c < Dt; c += 256) sd += b2f(qr[c]) * b2f(kr[c]);
    }
    #pragma unroll
    for (int off = 32; off; off >>= 1) { su += __shfl_xor(su, off, 64); sd += __shfl_xor(sd, off, 64); }
    __shared__ float rU[4], rD[4];
    if ((t & 63) == 0) { rU[t >> 6] = su; rD[t >> 6] = sd; }
    __syncthreads();
    if (t == 0) {
        su = (rU[0] + rU[1] + rU[2] + rU[3]) * (1.0f / Dt);
        sd = (rD[0] + rD[1] + rD[2] + rD[3]) * (1.0f / Dt);
        float u, d2; int emp = 0;
        if (hasU && hasD) {
            float m = fmaxf(su, sd);
            float eu = __expf(su - m), ed = __expf(sd - m);
            float inv = 1.0f / (eu + ed);
            u = eu * inv; d2 = ed * inv;
        } else if (hasU) { u = 1.0f; d2 = 0.0f; }
        else if (hasD)   { u = 0.0f; d2 = 1.0f; }
        else { u = d2 = 1.0f / 512.0f; emp = 1; }
        smU[gi] = u; smD[gi] = d2; emptyF[gi] = emp;
    }
}

// per-batch prefix of log(neigh superdiag)
__global__ __launch_bounds__(64)
void prefix_kernel(const float* __restrict__ prior, const float* __restrict__ smU,
                   const float* __restrict__ smD, float* __restrict__ P)
{
    int b = blockIdx.x;
    int l = threadIdx.x;
    float lv[8];
    float run = 0.0f;
    #pragma unroll
    for (int e = 0; e < 8; ++e) {
        int j = l * 8 + e;
        float lj = 0.0f;
        if (j < 511) {
            float pr = prior[((size_t)((b << 9) + j)) * 512 + j + 1];
            float nv = pr + (1.0f - pr) *
                       sqrtf(smU[(b << 9) + j] * smD[(b << 9) + j + 1] + 1e-9f);
            lj = logf(nv + 1e-9f);
        }
        lv[e] = run;
        run += lj;
    }
    float tot = run;
    float scan = tot;
    #pragma unroll
    for (int off = 1; off < 64; off <<= 1) {
        float n = __shfl_up(scan, off, 64);
        if (l >= off) scan += n;
    }
    float excl = scan - tot;
    #pragma unroll
    for (int e = 0; e < 8; ++e)
        P[b * 512 + l * 8 + e] = excl + lv[e];
}

// fused: neigh output + C output (f32 + bf16 scratch copy)
__global__ __launch_bounds__(512)
void neigh_cfill_kernel(const float* __restrict__ prior,
                        const float* __restrict__ smU, const float* __restrict__ smD,
                        const int* __restrict__ emptyF, const float* __restrict__ P,
                        float* __restrict__ ne_out, float* __restrict__ C_out,
                        ushort_t* __restrict__ CB)
{
    int bi = blockIdx.x;
    int j  = threadIdx.x;
    int b = bi >> 9, i = bi & 511;
    int bj = (b << 9) + j;
    const float invS = 1.0f / 512.0f;
    float fij, fji;
    if (j == i + 1)      { fij = smU[bi]; fji = smD[bj]; }
    else if (j == i - 1) { fij = smD[bi]; fji = smU[bj]; }
    else { fij = emptyF[bi] ? invS : 0.0f; fji = emptyF[bj] ? invS : 0.0f; }
    float val = sqrtf(fij * fji + 1e-9f);
    float pr = prior[(size_t)bi * 512 + j];
    float nv = pr + (1.0f - pr) * val;
    ne_out[(size_t)bi * 512 + j] = nv;
    float pi = P[bi], pj = P[bj];
    float v;
    if (j > i)      v = expf(pj - pi) + 1e-9f;
    else if (j < i) v = expf(pi - pj) + 1e-9f;
    else            v = nv;
    C_out[(size_t)bi * 512 + j] = v;
    CB[(size_t)bi * 512 + j] = f2b(v);
}

// ---------------- MFMA flash MHA, static-max softmax, bf16 C, XCD swizzle ----------
#define SMAX 12.0f
__global__ __launch_bounds__(256)
void mha_mfma(const ushort_t* __restrict__ q, const ushort_t* __restrict__ k,
              const ushort_t* __restrict__ vt, const int* __restrict__ am,
              const ushort_t* __restrict__ CB, ushort_t* __restrict__ ctx)
{
    __shared__ ushort_t Qs[64][72];
    __shared__ ushort_t Ks[64][72];
    __shared__ ushort_t Vs[64][72];   // [dk][key]
    __shared__ ushort_t Ps[64][72];
    int t = threadIdx.x;
    int w = t >> 6, l = t & 63;
    int lr = l & 15, lg = l >> 4;
    int kb8 = lg << 3;
    int bid = (blockIdx.z * 12 + blockIdx.y) * 8 + blockIdx.x;
    int sw = (bid & 7) * 192 + (bid >> 3);
    int qt = sw & 7, h = (sw >> 3) % 12, b = sw / 96;
    int hoff = h * 64;
    int q0 = qt * 64;
    int q0g = (b << 9) + q0;
    int myrow = w * 16 + lg * 4;

    #pragma unroll
    for (int i = 0; i < 2; ++i) {
        int c = t + i * 256;
        int r = c >> 3, dc = (c & 7) << 3;
        *(uint4*)&Qs[r][dc] = *(const uint4*)(q + (size_t)(q0g + r) * Dt + hoff + dc);
    }

    f32x4 oacc[4];
    #pragma unroll
    for (int n = 0; n < 4; ++n) oacc[n] = (f32x4)0.0f;
    float l_run[4] = {0.0f, 0.0f, 0.0f, 0.0f};

    for (int kb = 0; kb < 8; ++kb) {
        __syncthreads();
        #pragma unroll
        for (int i = 0; i < 2; ++i) {
            int c = t + i * 256;
            int r = c >> 3, dc = (c & 7) << 3;
            *(uint4*)&Ks[r][dc] =
                *(const uint4*)(k + (size_t)((b << 9) + kb * 64 + r) * Dt + hoff + dc);
            *(uint4*)&Vs[r][dc] =
                *(const uint4*)(vt + (size_t)(hoff + r) * Mrows + (b << 9) + kb * 64 + dc);
        }
        __syncthreads();

        int amv[4];
        #pragma unroll
        for (int n = 0; n < 4; ++n) amv[n] = am[(b << 9) + kb * 64 + n * 16 + lr];
        float cc[4][4];
        #pragma unroll
        for (int n = 0; n < 4; ++n)
            #pragma unroll
            for (int r = 0; r < 4; ++r)
                cc[n][r] = b2f(CB[(size_t)(q0g + myrow + r) * 512 + kb * 64 + n * 16 + lr]);

        f32x4 s[4];
        #pragma unroll
        for (int n = 0; n < 4; ++n) s[n] = (f32x4)0.0f;
        __builtin_amdgcn_s_setprio(1);
        #pragma unroll
        for (int ks = 0; ks < 2; ++ks) {
            bf16x8 aq = *(const bf16x8*)&Qs[w * 16 + lr][ks * 32 + kb8];
            #pragma unroll
            for (int n = 0; n < 4; ++n) {
                bf16x8 bk = *(const bf16x8*)&Ks[n * 16 + lr][ks * 32 + kb8];
                s[n] = mfma16(aq, bk, s[n]);
            }
        }
        __builtin_amdgcn_s_setprio(0);

        float pf[4][4];
        #pragma unroll
        for (int n = 0; n < 4; ++n) {
            int key = kb * 64 + n * 16 + lr;
            #pragma unroll
            for (int r = 0; r < 4; ++r) {
                int qrow = q0 + myrow + r;
                bool ok = (amv[n] != 0) || (key == qrow);
                float p = ok ? __expf(s[n][r] - SMAX) : 0.0f;
                pf[n][r] = p;
                l_run[r] += p;
            }
        }
        #pragma unroll
        for (int n = 0; n < 4; ++n)
            #pragma unroll
            for (int r = 0; r < 4; ++r)
                Ps[myrow + r][n * 16 + lr] = f2b(pf[n][r] * cc[n][r]);

        __builtin_amdgcn_s_setprio(1);
        #pragma unroll
        for (int ks = 0; ks < 2; ++ks) {
            bf16x8 ap = *(const bf16x8*)&Ps[w * 16 + lr][ks * 32 + kb8];
            #pragma unroll
            for (int n = 0; n < 4; ++n) {
                bf16x8 bv = *(const bf16x8*)&Vs[n * 16 + lr][ks * 32 + kb8];
                oacc[n] = mfma16(ap, bv, oacc[n]);
            }
        }
        __builtin_amdgcn_s_setprio(0);
    }
    #pragma unroll
    for (int r = 0; r < 4; ++r) {
        #pragma unroll
        for (int off = 1; off < 16; off <<= 1)
            l_run[r] += __shfl_xor(l_run[r], off, 64);
    }
    #pragma unroll
    for (int r = 0; r < 4; ++r) {
        float inv = 1.0f / l_run[r];
        #pragma unroll
        for (int n = 0; n < 4; ++n)
            ctx[(size_t)(q0g + myrow + r) * Dt + hoff + n * 16 + lr] =
                f2b(oacc[n][r] * inv);
    }
}

// -----------------------------------------------------------------------------------
extern "C" void kernel_launch(void* const* d_in, const int* in_sizes, int n_in,
                              void* d_out, int out_size, void* d_ws, size_t ws_size,
                              hipStream_t stream)
{
    (void)in_sizes; (void)n_in; (void)out_size; (void)ws_size;
    const float* x     = (const float*)d_in[0];
    const float* prior = (const float*)d_in[1];
    const int*   am    = (const int*)  d_in[2];
    const float* Wq = (const float*)d_in[3];   const float* bq = (const float*)d_in[4];
    const float* Wk = (const float*)d_in[5];   const float* bk = (const float*)d_in[6];
    const float* Wv = (const float*)d_in[7];   const float* bv = (const float*)d_in[8];
    const float* Wo = (const float*)d_in[9];   const float* bo = (const float*)d_in[10];
    const float* gWk = (const float*)d_in[11]; const float* gbk = (const float*)d_in[12];
    const float* gWq = (const float*)d_in[13]; const float* gbq = (const float*)d_in[14];
    const float* glng = (const float*)d_in[15]; const float* glnb = (const float*)d_in[16];
    const float* Wi = (const float*)d_in[17];  const float* bi = (const float*)d_in[18];
    const float* Wout = (const float*)d_in[19]; const float* bout = (const float*)d_in[20];
    const float* lng = (const float*)d_in[21]; const float* lnb = (const float*)d_in[22];

    float* out = (float*)d_out;
    float* o_layer = out;
    float* o_C     = out + (size_t)6291456;
    float* o_neigh = out + (size_t)10485760;
    float* o_attn  = out + (size_t)14680064;
    ushort_t* CB = (ushort_t*)o_attn;   // bf16 C scratch; Wo GEMM overwrites later

    // ---- workspace layout ----
    char* base = (char*)d_ws;
    ushort_t* WqkvT = (ushort_t*)(base);                  // [2304][768]
    ushort_t* gWqkT = (ushort_t*)(base + 3538944);        // [1536][768]
    ushort_t* WoT   = (ushort_t*)(base + 5898240);        // [768][768]
    ushort_t* WiT   = (ushort_t*)(base + 7077888);        // [3072][768]
    ushort_t* WoutT = (ushort_t*)(base + 11796480);       // [768][3072]
    float*    bqkv  = (float*)(base + 16515072);
    float*    gbqk  = (float*)(base + 16524288);
    float*    smU   = (float*)(base + 16530432);
    float*    smD   = (float*)(base + 16563200);
    float*    Ppre  = (float*)(base + 16595968);
    int*      emptyF= (int*)(base + 16628736);
    ushort_t* s0 = (ushort_t*)(base + 16661504);          // XB / CTXB
    ushort_t* s1 = (ushort_t*)(base + 29244416);          // HB / QB / AB16
    ushort_t* s2 = (ushort_t*)(base + 41827328);          // GQK / KB+VT / INTER
    ushort_t* XB = s0;    ushort_t* CTXB = s0;
    ushort_t* HB = s1;    ushort_t* QB = s1;   ushort_t* AB16 = s1;
    ushort_t* GQK = s2;   ushort_t* KB = s2;   ushort_t* INTER = s2;
    ushort_t* VT = s2 + 6291456;                          // [768][8192]

    // ---- weight prep ----
    tconv6_kernel<<<dim3(24, 24, 6), 256, 0, stream>>>(
        Wq, Wk, Wv, gWq, gWk, Wo,
        WqkvT, WqkvT + 589824, WqkvT + 1179648, gWqkT, gWqkT + 589824, WoT);
    tconv_kernel<<<dim3(96, 24), 256, 0, stream>>>(Wi, WiT, 768, 3072);
    tconv_kernel<<<dim3(24, 96), 256, 0, stream>>>(Wout, WoutT, 3072, 768);
    bconcat_kernel<<<15, 256, 0, stream>>>(bq, bk, bv, gbq, gbk, bqkv, gbqk);

    // ---- group attention ----
    lnx_kernel<<<8192, 256, 0, stream>>>(x, glng, glnb, XB, HB);
    gemm128<EPI_BF16><<<dim3(12, 64), 256, 0, stream>>>(
        HB, gWqkT, gbqk, nullptr, nullptr, GQK, nullptr, nullptr, 768, 768, 1536);
    group_scores_kernel<<<8192, 256, 0, stream>>>(GQK, am, smU, smD, emptyF);
    prefix_kernel<<<16, 64, 0, stream>>>(prior, smU, smD, Ppre);
    neigh_cfill_kernel<<<8192, 512, 0, stream>>>(prior, smU, smD, emptyF, Ppre,
                                                 o_neigh, o_C, CB);

    // ---- multi-head attention ----
    gemm128<EPI_QKV><<<dim3(18, 64), 256, 0, stream>>>(
        XB, WqkvT, bqkv, nullptr, nullptr, QB, KB, VT, 768, 768, 768);
    mha_mfma<<<dim3(8, 12, 16), 256, 0, stream>>>(QB, KB, VT, am, CB, CTXB);
    gemm128<EPI_DUAL><<<dim3(6, 64), 256, 0, stream>>>(
        CTXB, WoT, bo, nullptr, o_attn, AB16, nullptr, nullptr, 768, 768, 768);

    // ---- FFN, 2 chunks of 1536 over DI ----
    for (int c = 0; c < 2; ++c) {
        gemm128<EPI_GELU><<<dim3(12, 64), 256, 0, stream>>>(
            AB16, WiT + (size_t)c * 1536 * 768, bi + (size_t)c * 1536, nullptr,
            nullptr, INTER, nullptr, nullptr, 768, 768, 1536);
        if (c == 0)
            gemm128<EPI_RES><<<dim3(6, 64), 256, 0, stream>>>(
                INTER, WoutT + (size_t)c * 1536, bout, o_attn, o_layer, nullptr,
                nullptr, nullptr, 1536, 3072, 768);
        else
            gemm128<EPI_ACC><<<dim3(6, 64), 256, 0, stream>>>(
                INTER, WoutT + (size_t)c * 1536, nullptr, nullptr, o_layer, nullptr,
                nullptr, nullptr, 1536, 3072, 768);
    }
    ln_kernel<<<8192, 256, 0, stream>>>(o_layer, lng, lnb, o_layer);
}